// Round 6
// baseline (2883.365 us; speedup 1.0000x reference)
//
#include <hip/hip_runtime.h>
#include <hip/hip_bf16.h>
#include <cstdint>
#include <cstddef>

typedef __bf16 bf16_t;
typedef bf16_t bf16x8 __attribute__((ext_vector_type(8)));
typedef float  f32x4  __attribute__((ext_vector_type(4)));

#define TT    64
#define T_CTX 24
#define HOR   40
#define SL0   168     // raw(32)+h0(128)+pad(8): 2-way-free banks (stride 84 dw)
#define SL1   264     // h0(128)+h1(128)+pad(8)
#define NTH   512     // 8 waves

#define MFMA __builtin_amdgcn_mfma_f32_16x16x32_bf16

// ---- ws layout (bf16-element offsets; flag int at elem 0) ----
// E stream/wave: 52 frags = l0 [g][kt0..4] (kt0=folded raw) + l1 [g][kt0..7]
// D stream/wave: 60 frags = l0(20) + l1(32) + head(8)
// X stream/wave: 16 frags = [g][kt0..3] (enc-term in_Wih[:,128:256])
#define O_PKE   16
#define O_PKD   (O_PKE + 212992)
#define O_PKX   (O_PKD + 245760)
#define O_BIAS  (O_PKX + 65536)
#define O_HEADP (O_BIAS + 2048)
#define O_B2    (O_HEADP + 512)

struct Ptrs { const void* q[29]; };

__device__ __forceinline__ float sigm(float x) {
  return __builtin_amdgcn_rcpf(1.f + __expf(-x));
}
__device__ __forceinline__ float tanh_(float x) {
  return 1.f - 2.f * __builtin_amdgcn_rcpf(1.f + __expf(2.f * x));
}
__device__ __forceinline__ unsigned pk2(float a, float b) {
  unsigned ua = __float_as_uint(a), ub = __float_as_uint(b);
  ua = (ua + 0x7fffu + ((ua >> 16) & 1u)) >> 16;
  ub = (ub + 0x7fffu + ((ub >> 16) & 1u)) >> 16;
  return ua | (ub << 16);
}
__device__ __forceinline__ float uplo(unsigned p){ return __uint_as_float(p << 16); }
__device__ __forceinline__ float uphi(unsigned p){ return __uint_as_float(p & 0xffff0000u); }

// ================= dtype detector (validated r2) =================
__global__ void detect_kernel(const unsigned short* __restrict__ wsrc, int* __restrict__ flag)
{
  int tid = threadIdx.x;
  int wild = 0;
  for (int i = tid; i < 256; i += 64) {
    unsigned short b = wsrc[i];
    float v  = __uint_as_float(((unsigned)b) << 16);
    float av = fabsf(v);
    unsigned e = (b >> 7) & 0xff;
    if (av > 1000.f || e == 0xff || (((b & 0x7fff) != 0) && av < 1e-9f)) wild++;
  }
  for (int off = 32; off; off >>= 1) wild += __shfl_down(wild, off, 64);
  if (tid == 0) flag[0] = (wild > 16) ? 1 : 0;
}

// ================= prep: fold input-proj into l0 weights; pack per-gate streams ==========
__global__ void prep_kernel(Ptrs P, bf16_t* __restrict__ wb, const int* __restrict__ flag)
{
  const bool f32 = (flag[0] != 0);
  const int gtid = blockIdx.x * blockDim.x + threadIdx.x;
  const int gsz  = gridDim.x * blockDim.x;
  auto rd = [&](const void* src, int i) -> float {
    return f32 ? ((const float*)src)[i] : (float)((const bf16_t*)src)[i];
  };
  auto foldE = [&](int row, int c) -> float {   // (enc_Wih0 @ enc_W_in)[row][c]
    float a = 0.f;
    for (int k = 0; k < 128; ++k) a += rd(P.q[4], row * 128 + k) * rd(P.q[3], k * 10 + c);
    return a;
  };
  auto foldD = [&](int row, int c) -> float {   // (in_Wih[:, :128] @ node_W_in)[row][c]
    float a = 0.f;
    for (int k = 0; k < 128; ++k) a += rd(P.q[13], row * 256 + k) * rd(P.q[12], k * 10 + c);
    return a;
  };

  // E stream
  for (int i = gtid; i < 212992; i += gsz) {
    int w = i / 26624, r = i % 26624, f = r >> 9, e = r & 511;
    int ln = e >> 3, j = e & 7;
    int colk = ((ln >> 4) << 3) + j;
    float v;
    if (f < 20) {
      int g = f / 5, kt = f % 5;
      int row = g * 128 + w * 16 + (ln & 15);
      if (kt == 0) v = (colk < 10) ? foldE(row, colk) : 0.f;
      else         v = rd(P.q[5], row * 128 + (kt - 1) * 32 + colk);
    } else {
      int f2 = f - 20, g = f2 >> 3, kt = f2 & 7;
      int row = g * 128 + w * 16 + (ln & 15);
      v = (kt < 4) ? rd(P.q[8], row * 128 + kt * 32 + colk)
                   : rd(P.q[9], row * 128 + (kt - 4) * 32 + colk);
    }
    wb[O_PKE + i] = (bf16_t)v;
  }
  // D stream
  for (int i = gtid; i < 245760; i += gsz) {
    int w = i / 30720, r = i % 30720, f = r >> 9, e = r & 511;
    int ln = e >> 3, j = e & 7;
    int colk = ((ln >> 4) << 3) + j;
    float v;
    if (f < 20) {
      int g = f / 5, kt = f % 5;
      int row = g * 128 + w * 16 + (ln & 15);
      if (kt == 0) v = (colk < 10) ? foldD(row, colk) : 0.f;
      else         v = rd(P.q[14], row * 128 + (kt - 1) * 32 + colk);
    } else if (f < 52) {
      int f2 = f - 20, g = f2 >> 3, kt = f2 & 7;
      int row = g * 128 + w * 16 + (ln & 15);
      v = (kt < 4) ? rd(P.q[17], row * 128 + kt * 32 + colk)
                   : rd(P.q[18], row * 128 + (kt - 4) * 32 + colk);
    } else {
      int f2 = f - 52, h = f2 >> 2, kt = f2 & 3;
      int row = w * 16 + (ln & 15);
      v = rd(h ? P.q[25] : P.q[21], row * 128 + kt * 32 + colk);
    }
    wb[O_PKD + i] = (bf16_t)v;
  }
  // X stream
  for (int i = gtid; i < 65536; i += gsz) {
    int w = i >> 13, r = i & 8191, f = r >> 9, e = r & 511;
    int ln = e >> 3, j = e & 7;
    int colk = ((ln >> 4) << 3) + j;
    int g = f >> 2, kt = f & 3;
    int row = g * 128 + w * 16 + (ln & 15);
    wb[O_PKX + i] = (bf16_t)rd(P.q[13], row * 256 + 128 + kt * 32 + colk);
  }
  // biases / head params
  for (int i = gtid; i < 512; i += gsz) {
    wb[O_BIAS + i]        = (bf16_t)(rd(P.q[6],  i) + rd(P.q[7],  i));
    wb[O_BIAS + 512 + i]  = (bf16_t)(rd(P.q[10], i) + rd(P.q[11], i));
    wb[O_BIAS + 1024 + i] = (bf16_t)(rd(P.q[15], i) + rd(P.q[16], i));
    wb[O_BIAS + 1536 + i] = (bf16_t)(rd(P.q[19], i) + rd(P.q[20], i));
  }
  for (int i = gtid; i < 128; i += gsz) {
    wb[O_HEADP + i]       = (bf16_t)rd(P.q[22], i);
    wb[O_HEADP + 128 + i] = (bf16_t)rd(P.q[23], i);
    wb[O_HEADP + 256 + i] = (bf16_t)rd(P.q[26], i);
    wb[O_HEADP + 384 + i] = (bf16_t)rd(P.q[27], i);
  }
  if (gtid == 0) {
    wb[O_B2]     = (bf16_t)rd(P.q[24], 0);
    wb[O_B2 + 1] = (bf16_t)rd(P.q[28], 0);
  }
}

// ================= building blocks =================
template<int NF>
__device__ __forceinline__ void ldF(bf16x8 (&d)[NF], const bf16_t* __restrict__ pl, int f0) {
#pragma unroll
  for (int i = 0; i < NF; ++i) d[i] = *(const bf16x8*)(pl + (f0 + i) * 512);
}

// one gate-pass: ac[mt] += A(LDS) @ bf^T over NKT k-tiles
template<int NKT, int SS>
__device__ __forceinline__ void gpass(f32x4 (&ac)[4], const bf16_t* __restrict__ As,
                                      const bf16x8 (&bf)[NKT], int l, int q) {
#pragma unroll
  for (int kt = 0; kt < NKT; ++kt) {
#pragma unroll
    for (int mt = 0; mt < 4; ++mt) {
      bf16x8 a = *(const bf16x8*)(As + (mt * 16 + l) * SS + kt * 32 + q * 8);
      ac[mt] = MFMA(a, bf[kt], ac[mt], 0, 0, 0);
    }
  }
}

template<bool DUAL>
__device__ __forceinline__ void cell_up(f32x4 (&acc)[4][4], float (&c)[16],
                                        bf16_t* __restrict__ s1, bf16_t* __restrict__ s0,
                                        const bf16_t* __restrict__ bias,
                                        int wid, int l, int q)
{
  const int jc = wid * 16 + l;
  const float bi  = (float)bias[jc];
  const float bf_ = (float)bias[128 + jc];
  const float bg  = (float)bias[256 + jc];
  const float bo  = (float)bias[384 + jc];
#pragma unroll
  for (int mt = 0; mt < 4; ++mt) {
#pragma unroll
    for (int r = 0; r < 4; ++r) {
      float gi = acc[0][mt][r] + bi;
      float gf = acc[1][mt][r] + bf_;
      float gg = acc[2][mt][r] + bg;
      float go = acc[3][mt][r] + bo;
      float cn = sigm(gf) * c[mt * 4 + r] + sigm(gi) * tanh_(gg);
      float hh = sigm(go) * tanh_(cn);
      c[mt * 4 + r] = cn;
      const int row = mt * 16 + q * 4 + r;
      s1[row * SL1 + jc] = (bf16_t)hh;
      if (DUAL) s0[row * SL0 + jc] = (bf16_t)hh;
    }
  }
}

#define ZACC(A) _Pragma("unroll") for (int _g = 0; _g < 4; ++_g) \
                _Pragma("unroll") for (int _m = 0; _m < 4; ++_m) A[_g][_m] = f32x4{0.f,0.f,0.f,0.f};

// ================= persistent LSTM kernel =================
template<typename T>
__global__ __launch_bounds__(NTH, 1) void lstm_persist(
    const T* __restrict__ x, const T* __restrict__ coords, const T* __restrict__ env,
    const bf16_t* __restrict__ w, const int* __restrict__ flag, T* __restrict__ out)
{
  const bool want_f32 = (sizeof(T) == 4);
  if ((flag[0] != 0) != want_f32) return;

  __shared__ __align__(16) bf16_t s_l0[64 * SL0];     // [raw32 | h0 128]
  __shared__ __align__(16) bf16_t s_l1[64 * SL1];     // [h0 128 | h1 128]
  __shared__ __align__(16) bf16_t s_bias[2048];
  __shared__ __align__(16) unsigned s_ge[NTH * 36];   // enc-term cache, padded stride
  __shared__ float s_red[128];
  __shared__ float s_xc[64];

  const int tid  = threadIdx.x;
  const int wid  = tid >> 6;
  const int lane = tid & 63;
  const int l    = tid & 15;
  const int q    = (tid & 63) >> 4;
  const int node0 = blockIdx.x * 64;

  const bf16_t* plE = w + O_PKE + wid * 26624 + lane * 8;
  const bf16_t* plD = w + O_PKD + wid * 30720 + lane * 8;
  const bf16_t* plX = w + O_PKX + wid * 8192  + lane * 8;

  for (int i = tid; i < 2048; i += NTH) s_bias[i] = w[O_BIAS + i];
  for (int i = tid; i < 64 * SL0; i += NTH) s_l0[i] = (bf16_t)0.f;
  for (int i = tid; i < 64 * SL1; i += NTH) s_l1[i] = (bf16_t)0.f;

  const T* xb = x   + (size_t)(node0 + tid) * TT;
  const T* eb = env + (size_t)(node0 + tid) * 7 * TT;
  float cx = 0.f, cy = 0.f, pfx = 0.f;
  float pfe[7];
#pragma unroll
  for (int e = 0; e < 7; ++e) pfe[e] = 0.f;
  if (tid < 64) {
    cx  = (float)coords[(size_t)(node0 + tid) * 2 + 0];
    cy  = (float)coords[(size_t)(node0 + tid) * 2 + 1];
    pfx = (float)xb[0];
#pragma unroll
    for (int e = 0; e < 7; ++e) pfe[e] = (float)eb[e * TT];
  }

  float c0[16], c1[16];
#pragma unroll
  for (int i = 0; i < 16; ++i) { c0[i] = 0.f; c1[i] = 0.f; }

  bf16x8 bg0[5];  ldF<5>(bg0, plE, 0);
  bf16x8 bX0[4];
  __syncthreads();                                    // zeros done
  if (tid < 64) {
    s_l0[tid * SL0 + 0] = (bf16_t)pfx;
    s_l0[tid * SL0 + 1] = (bf16_t)cx;
    s_l0[tid * SL0 + 2] = (bf16_t)cy;
#pragma unroll
    for (int e = 0; e < 7; ++e) s_l0[tid * SL0 + 3 + e] = (bf16_t)pfe[e];
  }
  __syncthreads();                                    // raw0 ready; bg0 drained

  // ================= encoder =================
#pragma unroll 1
  for (int t = 0; t < T_CTX; ++t) {
    f32x4 acc[4][4]; ZACC(acc)
    bf16x8 bg1[5]; ldF<5>(bg1, plE, 5);
    gpass<5, SL0>(acc[0], s_l0, bg0, l, q);
    bf16x8 bg2[5]; ldF<5>(bg2, plE, 10);
    gpass<5, SL0>(acc[1], s_l0, bg1, l, q);
    bf16x8 bg3[5]; ldF<5>(bg3, plE, 15);
    gpass<5, SL0>(acc[2], s_l0, bg2, l, q);
    bf16x8 h1g0[8]; ldF<8>(h1g0, plE, 20);
    gpass<5, SL0>(acc[3], s_l0, bg3, l, q);
    __syncthreads();                                  // Ba: l0 A consumed
    cell_up<true>(acc, c0, s_l1, s_l0 + 32, s_bias, wid, l, q);
    bf16x8 h1g1[8]; ldF<8>(h1g1, plE, 28);
    __syncthreads();                                  // Bb: h0 ready
    ZACC(acc)
    bf16x8 h1g2[8]; ldF<8>(h1g2, plE, 36);
    gpass<8, SL1>(acc[0], s_l1, h1g0, l, q);
    bf16x8 h1g3[8]; ldF<8>(h1g3, plE, 44);
    gpass<8, SL1>(acc[1], s_l1, h1g1, l, q);
    if (tid < 64) {
      if (t + 1 < T_CTX) pfx = (float)xb[t + 1];
#pragma unroll
      for (int e = 0; e < 7; ++e) pfe[e] = (float)eb[e * TT + t + 1];
    }
    gpass<8, SL1>(acc[2], s_l1, h1g2, l, q);
    if (t < T_CTX - 1) ldF<5>(bg0, plE, 0);
    else               ldF<4>(bX0, plX, 0);
    gpass<8, SL1>(acc[3], s_l1, h1g3, l, q);
    __syncthreads();                                  // Bc: l1 A consumed
    cell_up<false>(acc, c1, s_l1 + 128, nullptr, s_bias + 512, wid, l, q);
    if (tid < 64 && t < T_CTX - 1) {
      s_l0[tid * SL0 + 0] = (bf16_t)pfx;
      s_l0[tid * SL0 + 1] = (bf16_t)cx;
      s_l0[tid * SL0 + 2] = (bf16_t)cy;
#pragma unroll
      for (int e = 0; e < 7; ++e) s_l0[tid * SL0 + 3 + e] = (bf16_t)pfe[e];
    }
    __syncthreads();                                  // Bd: h1 + raw ready
  }

  // ---- enc-term gemm (K=128) -> s_ge ----
  {
    f32x4 acc[4][4]; ZACC(acc)
    bf16x8 bX1[4]; ldF<4>(bX1, plX, 4);
    gpass<4, SL1>(acc[0], s_l1 + 128, bX0, l, q);
    bf16x8 bX2[4]; ldF<4>(bX2, plX, 8);
    gpass<4, SL1>(acc[1], s_l1 + 128, bX1, l, q);
    bf16x8 bX3[4]; ldF<4>(bX3, plX, 12);
    gpass<4, SL1>(acc[2], s_l1 + 128, bX2, l, q);
    gpass<4, SL1>(acc[3], s_l1 + 128, bX3, l, q);
#pragma unroll
    for (int g = 0; g < 4; ++g)
#pragma unroll
      for (int mt = 0; mt < 4; ++mt) {
        s_ge[tid * 36 + (g * 4 + mt) * 2 + 0] = pk2(acc[g][mt][0], acc[g][mt][1]);
        s_ge[tid * 36 + (g * 4 + mt) * 2 + 1] = pk2(acc[g][mt][2], acc[g][mt][3]);
      }
  }
  if (tid < 64) {
    s_xc[tid] = pfx;                                  // x[:, 23]
    s_l0[tid * SL0 + 0] = (bf16_t)pfx;
#pragma unroll
    for (int e = 0; e < 7; ++e) s_l0[tid * SL0 + 3 + e] = (bf16_t)pfe[e];   // env[24]
  }
  const float b2i = (float)w[O_B2];
  const float b2o = (float)w[O_B2 + 1];
  const float b1i = (float)w[O_HEADP + wid * 16 + l];
  const float w2i = (float)w[O_HEADP + 128 + wid * 16 + l];
  const float b1o = (float)w[O_HEADP + 256 + wid * 16 + l];
  const float w2o = (float)w[O_HEADP + 384 + wid * 16 + l];
  ldF<5>(bg0, plD, 0);
  __syncthreads();                                    // ge/raw/xc ready; bg0 drained

  // ================= decoder =================
#pragma unroll 1
  for (int s = 0; s < HOR; ++s) {
    const int t = T_CTX + s;
    f32x4 acc[4][4];
#pragma unroll
    for (int g = 0; g < 4; ++g)
#pragma unroll
      for (int mt = 0; mt < 4; ++mt) {
        unsigned u0 = s_ge[tid * 36 + (g * 4 + mt) * 2 + 0];
        unsigned u1 = s_ge[tid * 36 + (g * 4 + mt) * 2 + 1];
        acc[g][mt] = f32x4{uplo(u0), uphi(u0), uplo(u1), uphi(u1)};
      }
    bf16x8 bg1[5]; ldF<5>(bg1, plD, 5);
    gpass<5, SL0>(acc[0], s_l0, bg0, l, q);
    bf16x8 bg2[5]; ldF<5>(bg2, plD, 10);
    gpass<5, SL0>(acc[1], s_l0, bg1, l, q);
    bf16x8 bg3[5]; ldF<5>(bg3, plD, 15);
    gpass<5, SL0>(acc[2], s_l0, bg2, l, q);
    bf16x8 h1g0[8]; ldF<8>(h1g0, plD, 20);
    gpass<5, SL0>(acc[3], s_l0, bg3, l, q);
    __syncthreads();                                  // Ba
    cell_up<true>(acc, c0, s_l1, s_l0 + 32, s_bias + 1024, wid, l, q);
    bf16x8 h1g1[8]; ldF<8>(h1g1, plD, 28);
    __syncthreads();                                  // Bb
    ZACC(acc)
    bf16x8 h1g2[8]; ldF<8>(h1g2, plD, 36);
    gpass<8, SL1>(acc[0], s_l1, h1g0, l, q);
    bf16x8 h1g3[8]; ldF<8>(h1g3, plD, 44);
    gpass<8, SL1>(acc[1], s_l1, h1g1, l, q);
    bf16x8 hbi[4], hbo[4];
    ldF<4>(hbi, plD, 52);
    ldF<4>(hbo, plD, 56);
    gpass<8, SL1>(acc[2], s_l1, h1g2, l, q);
    if (tid < 64) {
      const int tn = (t + 1 < TT) ? t + 1 : t;
#pragma unroll
      for (int e = 0; e < 7; ++e) pfe[e] = (float)eb[e * TT + tn];
    }
    gpass<8, SL1>(acc[3], s_l1, h1g3, l, q);
    __syncthreads();                                  // Bc
    cell_up<false>(acc, c1, s_l1 + 128, nullptr, s_bias + 1536, wid, l, q);
    if (tid < 128) s_red[tid] = 0.f;
    __syncthreads();                                  // Bd
    // ---- heads ----
    f32x4 hi[4], ho[4];
#pragma unroll
    for (int m = 0; m < 4; ++m) { hi[m] = f32x4{0.f,0.f,0.f,0.f}; ho[m] = f32x4{0.f,0.f,0.f,0.f}; }
    gpass<4, SL1>(hi, s_l1 + 128, hbi, l, q);
    gpass<4, SL1>(ho, s_l1 + 128, hbo, l, q);
    ldF<5>(bg0, plD, 0);                              // next step's l0 g0 (drains at Be)
#pragma unroll
    for (int hd = 0; hd < 2; ++hd) {
      const float b1v = hd ? b1o : b1i;
      const float w2v = hd ? w2o : w2i;
#pragma unroll
      for (int mt = 0; mt < 4; ++mt)
#pragma unroll
        for (int r = 0; r < 4; ++r) {
          float val = fmaxf((hd ? ho[mt][r] : hi[mt][r]) + b1v, 0.f) * w2v;
          val += __shfl_xor(val, 1, 64);
          val += __shfl_xor(val, 2, 64);
          val += __shfl_xor(val, 4, 64);
          val += __shfl_xor(val, 8, 64);
          if (l == 0) atomicAdd(&s_red[hd * 64 + mt * 16 + q * 4 + r], val);
        }
    }
    __syncthreads();                                  // Be
    if (tid < 64) {
      float xc = s_xc[tid];
      float si = sigm(s_red[tid] + b2i);
      float so = sigm(s_red[64 + tid] + b2o);
      float xn = xc + si - so * xc;
      s_xc[tid] = xn;
      out[(size_t)(node0 + tid) * HOR + s] = (T)xn;
      s_l0[tid * SL0 + 0] = (bf16_t)xn;
      s_l0[tid * SL0 + 1] = (bf16_t)cx;
      s_l0[tid * SL0 + 2] = (bf16_t)cy;
#pragma unroll
      for (int e = 0; e < 7; ++e) s_l0[tid * SL0 + 3 + e] = (bf16_t)pfe[e];
    }
    __syncthreads();                                  // Bf: raw + xc ready
  }
}

extern "C" void kernel_launch(void* const* d_in, const int* in_sizes, int n_in,
                              void* d_out, int out_size, void* d_ws, size_t ws_size,
                              hipStream_t stream) {
  (void)in_sizes; (void)n_in; (void)out_size; (void)ws_size;
  Ptrs P;
  for (int i = 0; i < 29; ++i) P.q[i] = d_in[i];
  int*    flag = (int*)d_ws;
  bf16_t* w    = (bf16_t*)d_ws;

  detect_kernel<<<1, 64, 0, stream>>>((const unsigned short*)d_in[4], flag);
  prep_kernel<<<256, 256, 0, stream>>>(P, w, flag);
  lstm_persist<float><<<256, NTH, 0, stream>>>(
      (const float*)d_in[0], (const float*)d_in[1], (const float*)d_in[2],
      w, flag, (float*)d_out);
  lstm_persist<__bf16><<<256, NTH, 0, stream>>>(
      (const __bf16*)d_in[0], (const __bf16*)d_in[1], (const __bf16*)d_in[2],
      w, flag, (__bf16*)d_out);
}